// Round 3
// baseline (153.620 us; speedup 1.0000x reference)
//
#include <hip/hip_runtime.h>

// maTransformerBlock fused kernel for MI355X (gfx950)
//
// Shuffle algebra: sd[b',n',c] = d[(32 b' + n') mod 32768, 3*((32 b' + n') div 32768) + c]
// With b' = k*1024 + j  (k in [0,32), j in [0,1024)):
//   source batch = 32 j + n', chunk = k.
// => block j handles source batches 32j..32j+31 and output batches {k*1024 + j}.

constexpr int NB       = 32;    // source batches per block
constexpr int THREADS  = 256;
constexpr int NBLOCKS  = 1024;
constexpr int SSTRIDE  = 316;   // stage slot stride (floats); rows padded to 104 (f4-aligned)
constexpr int PSTRIDE4 = 33;    // attn plane stride in float4 (padded: 33 odd -> bank spread)

__global__ __launch_bounds__(THREADS, 2)
void fused_matx(const float* __restrict__ dna,
                const float* __restrict__ prot,
                const float* __restrict__ wdna,
                const float* __restrict__ wprot,
                const float* __restrict__ wlin,
                const float* __restrict__ blin,
                float* __restrict__ out)
{
    __shared__ float  s_stage[NB * SSTRIDE];   // 10112 f = 40448 B (raw input tile)
    __shared__ float4 s_d4[NB * PSTRIDE4];     // [row r][chunk ob] relu(conv(dna))  16896 B
    __shared__ float4 s_p4[NB * PSTRIDE4];     // [row q][chunk ob] relu(conv(prot)) 16896 B
    __shared__ float  s_wd[32];
    __shared__ float  s_wp[168];
    __shared__ float  s_wl[192];
    __shared__ float  s_bl[2];

    const int tid = threadIdx.x;
    const int j   = blockIdx.x;

    // ---- weights -> LDS (read later, after the first two barriers) ----
    if (tid < 32)                 s_wd[tid]      = wdna[tid];
    if (tid >= 32 && tid < 200)   s_wp[tid - 32] = wprot[tid - 32];
    if (tid < 192)                s_wl[tid]      = wlin[tid];
    if (tid < 2)                  s_bl[tid]      = blin[tid];

    const int cs = tid >> 3;      // conv: source-batch slot 0..31
    const int xb = tid & 7;       // conv: x-block 0..7
    const int x0 = xb * 12;       // 12 conv outputs per thread

    // ================= DNA conv: 2 passes x 2 channels =================
    float dacc[12];
#pragma unroll
    for (int o = 0; o < 12; ++o) dacc[o] = 0.f;

    const float* dbase = dna + (size_t)j * NB * 412;   // 4*103 = 412 floats/batch
    for (int q = 0; q < 2; ++q) {
        __syncthreads();
        // stage 32*206 = 6592 floats (channels 2q, 2q+1 of all 32 batches), coalesced
        {
            int i = tid;
#pragma unroll 4
            for (int itr = 0; itr < 25; ++itr, i += THREADS) {
                int s   = i / 206;
                int rem = i - s * 206;
                int cc  = (rem >= 103) ? 1 : 0;            // row pad: +1 per row
                s_stage[s * SSTRIDE + rem + cc] = dbase[s * 412 + q * 206 + rem];
            }
            if (i < NB * 206) {
                int s   = i / 206;
                int rem = i - s * 206;
                int cc  = (rem >= 103) ? 1 : 0;
                s_stage[s * SSTRIDE + rem + cc] = dbase[s * 412 + q * 206 + rem];
            }
        }
        __syncthreads();
#pragma unroll
        for (int cc = 0; cc < 2; ++cc) {
            float w[8];
#pragma unroll
            for (int f = 0; f < 8; ++f) w[f] = s_wd[(q * 2 + cc) * 8 + f];  // broadcast
            float in[20];
            const float4* src = (const float4*)&s_stage[cs * SSTRIDE + cc * 104 + x0];
#pragma unroll
            for (int t = 0; t < 5; ++t) {                  // 5 aligned ds_read_b128
                float4 v = src[t];
                in[4*t+0] = v.x; in[4*t+1] = v.y; in[4*t+2] = v.z; in[4*t+3] = v.w;
            }
#pragma unroll
            for (int f = 0; f < 8; ++f)
#pragma unroll
                for (int o = 0; o < 12; ++o)
                    dacc[o] = fmaf(in[o + f], w[f], dacc[o]);
        }
    }
    // write relu'd dna conv as float4 planes [row=cs][ob], ob = 4*xb + u
#pragma unroll
    for (int u = 0; u < 4; ++u) {
        float4 v;
        v.x = fmaxf(dacc[3*u+0], 0.f);
        v.y = fmaxf(dacc[3*u+1], 0.f);
        v.z = fmaxf(dacc[3*u+2], 0.f);
        v.w = 0.f;
        s_d4[cs * PSTRIDE4 + 4 * xb + u] = v;
    }

    // ================= PROT conv: 7 passes x 3 channels =================
    float pacc[12];
#pragma unroll
    for (int o = 0; o < 12; ++o) pacc[o] = 0.f;

    const float* pbase = prot + (size_t)j * NB * 2163;  // 21*103 = 2163 floats/batch
    for (int q = 0; q < 7; ++q) {
        __syncthreads();
        // stage 32*309 = 9888 floats (channels 3q..3q+2), coalesced scalar
        {
            int i = tid;
#pragma unroll 4
            for (int itr = 0; itr < 38; ++itr, i += THREADS) {
                int s   = i / 309;
                int rem = i - s * 309;
                int cc  = (rem >= 206) ? 2 : ((rem >= 103) ? 1 : 0);
                s_stage[s * SSTRIDE + rem + cc] = pbase[s * 2163 + q * 309 + rem];
            }
            if (i < NB * 309) {
                int s   = i / 309;
                int rem = i - s * 309;
                int cc  = (rem >= 206) ? 2 : ((rem >= 103) ? 1 : 0);
                s_stage[s * SSTRIDE + rem + cc] = pbase[s * 2163 + q * 309 + rem];
            }
        }
        __syncthreads();
#pragma unroll
        for (int cc = 0; cc < 3; ++cc) {
            float w[8];
#pragma unroll
            for (int f = 0; f < 8; ++f) w[f] = s_wp[(q * 3 + cc) * 8 + f];
            float in[20];
            const float4* src = (const float4*)&s_stage[cs * SSTRIDE + cc * 104 + x0];
#pragma unroll
            for (int t = 0; t < 5; ++t) {
                float4 v = src[t];
                in[4*t+0] = v.x; in[4*t+1] = v.y; in[4*t+2] = v.z; in[4*t+3] = v.w;
            }
#pragma unroll
            for (int f = 0; f < 8; ++f)
#pragma unroll
                for (int o = 0; o < 12; ++o)
                    pacc[o] = fmaf(in[o + f], w[f], pacc[o]);
        }
    }
#pragma unroll
    for (int u = 0; u < 4; ++u) {
        float4 v;
        v.x = fmaxf(pacc[3*u+0], 0.f);
        v.y = fmaxf(pacc[3*u+1], 0.f);
        v.z = fmaxf(pacc[3*u+2], 0.f);
        v.w = 0.f;
        s_p4[cs * PSTRIDE4 + 4 * xb + u] = v;
    }
    __syncthreads();

    // ================= attention (32x32, d=3) + linear =================
    const float scale = 0.5773502691896258f;   // 1/sqrt(3)
    const int qr   = tid & 31;                  // query row
    const int obHi = tid >> 5;                  // 2 distinct per wave -> LDS broadcast
    const float wl00 = s_wl[3 * qr + 0], wl01 = s_wl[3 * qr + 1], wl02 = s_wl[3 * qr + 2];
    const float wl10 = s_wl[96 + 3 * qr + 0], wl11 = s_wl[96 + 3 * qr + 1], wl12 = s_wl[96 + 3 * qr + 2];
    const float bl0 = s_bl[0], bl1 = s_bl[1];

    for (int it = 0; it < 4; ++it) {
        const int ob = obHi * 4 + it;          // chunk k = output batch ob*1024 + j
        const float4 qv = s_p4[qr * PSTRIDE4 + ob];

        float lg[32];
        float mx = -1e30f;
#pragma unroll
        for (int r = 0; r < 32; ++r) {         // one broadcast ds_read_b128 per key
            float4 dv = s_d4[r * PSTRIDE4 + ob];
            float l = fmaf(qv.x, dv.x, fmaf(qv.y, dv.y, qv.z * dv.z)) * scale;
            lg[r] = l;
            mx = fmaxf(mx, l);
        }
        float sum = 0.f;
#pragma unroll
        for (int r = 0; r < 32; ++r) {
            float e = __expf(lg[r] - mx);
            lg[r] = e;
            sum += e;
        }
        const float inv = 1.f / sum;
        float v0 = 0.f, v1 = 0.f, v2 = 0.f;
#pragma unroll
        for (int r = 0; r < 32; ++r) {
            float4 dv = s_d4[r * PSTRIDE4 + ob];
            v0 = fmaf(lg[r], dv.x, v0);
            v1 = fmaf(lg[r], dv.y, v1);
            v2 = fmaf(lg[r], dv.z, v2);
        }
        v0 *= inv; v1 *= inv; v2 *= inv;

        // linear: out2[oi] = sum_{q,c} wl[oi][3q+c] * val[q][c]; reduce over 32 q-lanes
        float o0 = wl00 * v0 + wl01 * v1 + wl02 * v2;
        float o1 = wl10 * v0 + wl11 * v1 + wl12 * v2;
#pragma unroll
        for (int m = 16; m >= 1; m >>= 1) {    // stays within each 32-lane half
            o0 += __shfl_xor(o0, m);
            o1 += __shfl_xor(o1, m);
        }
        if (qr == 0) {
            const int bp = (ob << 10) + j;     // output batch index
            float2 res;
            res.x = o0 + bl0;
            res.y = o1 + bl1;
            *reinterpret_cast<float2*>(&out[(size_t)bp * 2]) = res;
        }
    }
}

extern "C" void kernel_launch(void* const* d_in, const int* in_sizes, int n_in,
                              void* d_out, int out_size, void* d_ws, size_t ws_size,
                              hipStream_t stream) {
    const float* dna   = (const float*)d_in[0];
    const float* prot  = (const float*)d_in[1];
    const float* wdna  = (const float*)d_in[2];
    const float* wprot = (const float*)d_in[3];
    const float* wlin  = (const float*)d_in[4];
    const float* blin  = (const float*)d_in[5];
    float* out = (float*)d_out;

    fused_matx<<<NBLOCKS, THREADS, 0, stream>>>(dna, prot, wdna, wprot, wlin, blin, out);
}

// Round 4
// 80.227 us; speedup vs baseline: 1.9148x; 1.9148x over previous
//
#include <hip/hip_runtime.h>

// maTransformerBlock fused kernel for MI355X (gfx950)
//
// Shuffle algebra: with output batch b' = k*1024 + j (k in [0,32), j in [0,1024)):
//   source batch = 32 j + n', chunk = k.
// => block j handles source batches 32j..32j+31 and output batches {k*1024 + j}.
//
// R3: software-pipelined staging (T14 async-STAGE split). Each phase's global
// loads are issued one phase EARLY into registers (pfA/pfB ping-pong) and only
// committed to LDS after the barrier, so HBM drain overlaps conv compute.

constexpr int NB       = 32;    // source batches per block
constexpr int THREADS  = 256;
constexpr int NBLOCKS  = 1024;
constexpr int SSTRIDE  = 316;   // stage slot stride (floats); rows padded to 104 (f4-aligned)
constexpr int PSTRIDE4 = 33;    // attn plane stride in float4 (odd -> bank spread)
constexpr int PF_D     = 26;    // ceil(32*206/256) regs per thread, dna phase
constexpr int PF_P     = 39;    // ceil(32*309/256) regs per thread, prot phase
constexpr int CNT_D    = NB * 206;   // 6592 floats per dna phase
constexpr int CNT_P    = NB * 309;   // 9888 floats per prot phase

__global__ __launch_bounds__(THREADS, 2)
void fused_matx(const float* __restrict__ dna,
                const float* __restrict__ prot,
                const float* __restrict__ wdna,
                const float* __restrict__ wprot,
                const float* __restrict__ wlin,
                const float* __restrict__ blin,
                float* __restrict__ out)
{
    __shared__ float  s_stage[NB * SSTRIDE];   // 40448 B (raw input tile, padded rows)
    __shared__ float4 s_d4[NB * PSTRIDE4];     // [row r][chunk ob] relu(conv(dna))  16896 B
    __shared__ float4 s_p4[NB * PSTRIDE4];     // [row q][chunk ob] relu(conv(prot)) 16896 B
    __shared__ float  s_wd[32];
    __shared__ float  s_wp[168];
    __shared__ float  s_wl[192];
    __shared__ float  s_bl[2];

    const int tid = threadIdx.x;
    const int j   = blockIdx.x;

    // ---- weights -> LDS (visible after the first barrier before any compute) ----
    if (tid < 32)                 s_wd[tid]      = wdna[tid];
    if (tid >= 32 && tid < 200)   s_wp[tid - 32] = wprot[tid - 32];
    if (tid < 192)                s_wl[tid]      = wlin[tid];
    if (tid < 2)                  s_bl[tid]      = blin[tid];

    const int cs = tid >> 3;      // conv: source-batch slot 0..31
    const int xb = tid & 7;       // conv: x-block 0..7
    const int x0 = xb * 12;       // 12 conv outputs per thread

    const float* dbase = dna  + (size_t)j * NB * 412;    // 4*103 floats/batch
    const float* pbase = prot + (size_t)j * NB * 2163;   // 21*103 floats/batch

    float dacc[12], pacc[12];
#pragma unroll
    for (int o = 0; o < 12; ++o) { dacc[o] = 0.f; pacc[o] = 0.f; }

    // ---- prefetch: issue global loads for a phase into registers ----
    auto pf_dna = [&](int q, float (&pf)[PF_P]) {
        int rem  = (tid >= 206) ? tid - 206 : tid;
        int soff = (tid >= 206) ? 206 : 0;               // 206*s
        const float* gb = dbase + q * 206;               // g = i + 206*s + 206*q
#pragma unroll
        for (int k = 0; k < PF_D; ++k) {
            int i = tid + 256 * k;
            if (i < CNT_D) pf[k] = gb[i + soff];
            rem += 256;
            if (rem >= 206) { rem -= 206; soff += 206; }
            if (rem >= 206) { rem -= 206; soff += 206; }  // 256 > 206: up to 2 wraps
        }
    };
    auto pf_prot = [&](int q, float (&pf)[PF_P]) {
        int rem  = tid;
        int soff = 0;                                    // 1854*s
        const float* gb = pbase + q * 309;               // g = i + 1854*s + 309*q
#pragma unroll
        for (int k = 0; k < PF_P; ++k) {
            int i = tid + 256 * k;
            if (i < CNT_P) pf[k] = gb[i + soff];
            rem += 256;
            if (rem >= 309) { rem -= 309; soff += 1854; }
        }
    };
    // ---- commit: registers -> padded LDS rows ----
    auto wr_dna = [&](float (&pf)[PF_P]) {
        int rem  = (tid >= 206) ? tid - 206 : tid;
        int sstr = (tid >= 206) ? SSTRIDE : 0;
#pragma unroll
        for (int k = 0; k < PF_D; ++k) {
            int i = tid + 256 * k;
            if (i < CNT_D) {
                int cc = (rem >= 103) ? 1 : 0;           // row pad: +1 per row
                s_stage[sstr + rem + cc] = pf[k];
            }
            rem += 256;
            if (rem >= 206) { rem -= 206; sstr += SSTRIDE; }
            if (rem >= 206) { rem -= 206; sstr += SSTRIDE; }
        }
    };
    auto wr_prot = [&](float (&pf)[PF_P]) {
        int rem  = tid;
        int sstr = 0;
#pragma unroll
        for (int k = 0; k < PF_P; ++k) {
            int i = tid + 256 * k;
            if (i < CNT_P) {
                int cc = (rem >= 206) ? 2 : ((rem >= 103) ? 1 : 0);
                s_stage[sstr + rem + cc] = pf[k];
            }
            rem += 256;
            if (rem >= 309) { rem -= 309; sstr += SSTRIDE; }
        }
    };
    // ---- conv compute from LDS (aligned b128 sliding window) ----
    auto compute_dna = [&](int q) {
#pragma unroll
        for (int cc = 0; cc < 2; ++cc) {
            float w[8];
#pragma unroll
            for (int f = 0; f < 8; ++f) w[f] = s_wd[(q * 2 + cc) * 8 + f];
            float in[20];
            const float4* src = (const float4*)&s_stage[cs * SSTRIDE + cc * 104 + x0];
#pragma unroll
            for (int t = 0; t < 5; ++t) {
                float4 v = src[t];
                in[4*t+0] = v.x; in[4*t+1] = v.y; in[4*t+2] = v.z; in[4*t+3] = v.w;
            }
#pragma unroll
            for (int f = 0; f < 8; ++f)
#pragma unroll
                for (int o = 0; o < 12; ++o)
                    dacc[o] = fmaf(in[o + f], w[f], dacc[o]);
        }
    };
    auto compute_prot = [&](int q) {
#pragma unroll
        for (int cc = 0; cc < 3; ++cc) {
            float w[8];
#pragma unroll
            for (int f = 0; f < 8; ++f) w[f] = s_wp[(q * 3 + cc) * 8 + f];
            float in[20];
            const float4* src = (const float4*)&s_stage[cs * SSTRIDE + cc * 104 + x0];
#pragma unroll
            for (int t = 0; t < 5; ++t) {
                float4 v = src[t];
                in[4*t+0] = v.x; in[4*t+1] = v.y; in[4*t+2] = v.z; in[4*t+3] = v.w;
            }
#pragma unroll
            for (int f = 0; f < 8; ++f)
#pragma unroll
                for (int o = 0; o < 12; ++o)
                    pacc[o] = fmaf(in[o + f], w[f], pacc[o]);
        }
    };

    // ================= pipelined phases =================
    float pfA[PF_P], pfB[PF_P];

    pf_dna(0, pfA);
    wr_dna(pfA);                 // waits only on pfA loads
    pf_dna(1, pfB);              // in flight across barrier + compute
    __syncthreads();
    compute_dna(0);

    __syncthreads();
    wr_dna(pfB);
    pf_prot(0, pfA);
    __syncthreads();
    compute_dna(1);
#pragma unroll
    for (int u = 0; u < 4; ++u) {                    // store relu'd dna conv
        float4 v;
        v.x = fmaxf(dacc[3*u+0], 0.f);
        v.y = fmaxf(dacc[3*u+1], 0.f);
        v.z = fmaxf(dacc[3*u+2], 0.f);
        v.w = 0.f;
        s_d4[cs * PSTRIDE4 + 4 * xb + u] = v;
    }

    __syncthreads(); wr_prot(pfA); pf_prot(1, pfB); __syncthreads(); compute_prot(0);
    __syncthreads(); wr_prot(pfB); pf_prot(2, pfA); __syncthreads(); compute_prot(1);
    __syncthreads(); wr_prot(pfA); pf_prot(3, pfB); __syncthreads(); compute_prot(2);
    __syncthreads(); wr_prot(pfB); pf_prot(4, pfA); __syncthreads(); compute_prot(3);
    __syncthreads(); wr_prot(pfA); pf_prot(5, pfB); __syncthreads(); compute_prot(4);
    __syncthreads(); wr_prot(pfB); pf_prot(6, pfA); __syncthreads(); compute_prot(5);
    __syncthreads(); wr_prot(pfA);                  __syncthreads(); compute_prot(6);

#pragma unroll
    for (int u = 0; u < 4; ++u) {                    // store relu'd prot conv
        float4 v;
        v.x = fmaxf(pacc[3*u+0], 0.f);
        v.y = fmaxf(pacc[3*u+1], 0.f);
        v.z = fmaxf(pacc[3*u+2], 0.f);
        v.w = 0.f;
        s_p4[cs * PSTRIDE4 + 4 * xb + u] = v;
    }
    __syncthreads();

    // ================= attention (32x32, d=3) + linear =================
    const float scale = 0.5773502691896258f;   // 1/sqrt(3)
    const int qr   = tid & 31;                  // query row
    const int obHi = tid >> 5;                  // 2 distinct per wave -> LDS broadcast
    const float wl00 = s_wl[3 * qr + 0], wl01 = s_wl[3 * qr + 1], wl02 = s_wl[3 * qr + 2];
    const float wl10 = s_wl[96 + 3 * qr + 0], wl11 = s_wl[96 + 3 * qr + 1], wl12 = s_wl[96 + 3 * qr + 2];
    const float bl0 = s_bl[0], bl1 = s_bl[1];

    for (int it = 0; it < 4; ++it) {
        const int ob = obHi * 4 + it;          // chunk k = output batch ob*1024 + j
        const float4 qv = s_p4[qr * PSTRIDE4 + ob];

        float lg[32];
        float mx = -1e30f;
#pragma unroll
        for (int r = 0; r < 32; ++r) {         // one broadcast ds_read_b128 per key
            float4 dv = s_d4[r * PSTRIDE4 + ob];
            float l = fmaf(qv.x, dv.x, fmaf(qv.y, dv.y, qv.z * dv.z)) * scale;
            lg[r] = l;
            mx = fmaxf(mx, l);
        }
        float sum = 0.f;
#pragma unroll
        for (int r = 0; r < 32; ++r) {
            float e = __expf(lg[r] - mx);
            lg[r] = e;
            sum += e;
        }
        const float inv = 1.f / sum;
        float v0 = 0.f, v1 = 0.f, v2 = 0.f;
#pragma unroll
        for (int r = 0; r < 32; ++r) {
            float4 dv = s_d4[r * PSTRIDE4 + ob];
            v0 = fmaf(lg[r], dv.x, v0);
            v1 = fmaf(lg[r], dv.y, v1);
            v2 = fmaf(lg[r], dv.z, v2);
        }
        v0 *= inv; v1 *= inv; v2 *= inv;

        // linear: out2[oi] = sum_{q,c} wl[oi][3q+c] * val[q][c]; reduce over 32 q-lanes
        float o0 = wl00 * v0 + wl01 * v1 + wl02 * v2;
        float o1 = wl10 * v0 + wl11 * v1 + wl12 * v2;
#pragma unroll
        for (int m = 16; m >= 1; m >>= 1) {    // stays within each 32-lane half
            o0 += __shfl_xor(o0, m);
            o1 += __shfl_xor(o1, m);
        }
        if (qr == 0) {
            const int bp = (ob << 10) + j;     // output batch index
            float2 res;
            res.x = o0 + bl0;
            res.y = o1 + bl1;
            *reinterpret_cast<float2*>(&out[(size_t)bp * 2]) = res;
        }
    }
}

extern "C" void kernel_launch(void* const* d_in, const int* in_sizes, int n_in,
                              void* d_out, int out_size, void* d_ws, size_t ws_size,
                              hipStream_t stream) {
    const float* dna   = (const float*)d_in[0];
    const float* prot  = (const float*)d_in[1];
    const float* wdna  = (const float*)d_in[2];
    const float* wprot = (const float*)d_in[3];
    const float* wlin  = (const float*)d_in[4];
    const float* blin  = (const float*)d_in[5];
    float* out = (float*)d_out;

    fused_matx<<<NBLOCKS, THREADS, 0, stream>>>(dna, prot, wdna, wprot, wlin, blin, out);
}